// Round 6
// baseline (307.598 us; speedup 1.0000x reference)
//
#include <hip/hip_runtime.h>
#include <math.h>

// Problem constants
#define NF 5
#define NB 8
#define NC 64
#define HW 16384
#define NK 320               // NF*NC
#define EN_FLOATS (NB*NC*8)  // per (b,c): E0..E3, N0..N3

#define WIN 512              // k1 spatial window (floats)
#define NT  40               // k-tiles of 8 rows (320 total)

__device__ __forceinline__ float redsum64(float v){
#pragma unroll
    for (int m = 1; m < 64; m <<= 1) v += __shfl_xor(v, m, 64);
    return v;
}

// ---------------- k0z: zero EN + y ----------------
__global__ void k0z(float* __restrict__ EN, float* __restrict__ y){
    const int blk = blockIdx.x, tid = threadIdx.x;
    float4 z = make_float4(0.f,0.f,0.f,0.f);
    if (blk == 0){                       // EN: 4096 floats = 1024 float4
#pragma unroll
        for (int j=0; j<4; ++j)
            reinterpret_cast<float4*>(EN)[tid*4 + j] = z;
    } else {                             // y: 131072 floats, 64 blocks x 512 f4
        int i = (blk - 1)*512 + tid*2;
        reinterpret_cast<float4*>(y)[i]     = z;
        reinterpret_cast<float4*>(y)[i + 1] = z;
    }
}

// ---------------- k1: GEMM + E/N, 2-deep pipelined LDS staging ----------------
// Round-4 post-mortem: 1-deep staging at 2 blocks/CU left per-tile wall 3270cy
// vs 2048cy FMA issue (VALUBusy 37%). This kernel (= round-5 phase 1, whose
// logic was audited; round-5 failed only in its cooperative LAUNCH):
//  - WIN=512 -> 32 KB LDS -> 4 blocks/CU, 16 waves/CU (2x round 4).
//  - 2-tile-deep: iter kt ds_writes T(kt+1) (compiler inserts counted vmcnt)
//    and issues global loads for T(kt+3) -> ~2 tiles of latency cover.
//  - Stage reads are 2 KB contiguous per row per block (channel-balanced HBM).
//  - Grid 1024 = 8b x 32win x 4cgrp; the 4 cgrp siblings sharing an X panel
//    sit on one XCD (blk&7) -> panel read once from HBM, 4x from that L2.
//  - Weights: direct s_load from origin_w rows (uniform addr; no pack pass).
//  - Phase B: E/N in-register from accs, shfl butterflies, lane0 atomics.
__global__ __launch_bounds__(256, 4) void k1_fused(
    const float* __restrict__ inp, const float* __restrict__ Wg,
    const float* __restrict__ bias, float* __restrict__ EN)
{
    __shared__ float S[2*8*WIN];    // 32 KB: two 8x512 tiles

    const int tid = threadIdx.x;
    const int l    = tid & 63;
    const int wv   = __builtin_amdgcn_readfirstlane(tid >> 6);  // 0..3
    const int blk  = blockIdx.x;
    const int xcd  = blk & 7;
    const int q    = blk >> 3;               // 0..127
    const int cgrp = q & 3;
    const int unit = xcd*32 + (q >> 2);      // 0..255 = (b, win)
    const int b    = unit >> 5;
    const int sbase= (unit & 31) << 9;       // 512-float window
    const int cf   = (cgrp << 4) + (wv << 2);// first of this wave's 4 channels
    const int hi   = tid >> 7;               // 0/1: row parity in stage
    const int col  = (tid & 127) << 2;       // stage column (float)

    // uniform weight row pointers -> s_load
    const float* w0r = Wg + (size_t)(cf+0)*NK;
    const float* w1r = Wg + (size_t)(cf+1)*NK;
    const float* w2r = Wg + (size_t)(cf+2)*NK;
    const float* w3r = Wg + (size_t)(cf+3)*NK;

    // accumulators: channel j (0..3) x part p (0..1), s = sbase + p*256 + 4l
    float4 c0p0,c0p1,c1p0,c1p1,c2p0,c2p1,c3p0,c3p1;
    {
        float4 bv = *reinterpret_cast<const float4*>(bias + cf);
        c0p0=c0p1 = make_float4(bv.x,bv.x,bv.x,bv.x);
        c1p0=c1p1 = make_float4(bv.y,bv.y,bv.y,bv.y);
        c2p0=c2p1 = make_float4(bv.z,bv.z,bv.z,bv.z);
        c3p0=c3p1 = make_float4(bv.w,bv.w,bv.w,bv.w);
    }

#define XADDR(K) (inp + ((size_t)((((K)>>6))*NB + b)*NC + ((K)&63))*HW + sbase + col)
#define LOADSET(R0,R1,R2,R3, KT) { \
    R0 = *reinterpret_cast<const float4*>(XADDR((KT)*8 + 0 + hi)); \
    R1 = *reinterpret_cast<const float4*>(XADDR((KT)*8 + 2 + hi)); \
    R2 = *reinterpret_cast<const float4*>(XADDR((KT)*8 + 4 + hi)); \
    R3 = *reinterpret_cast<const float4*>(XADDR((KT)*8 + 6 + hi)); }
#define WRITESET(R0,R1,R2,R3, BUF) { \
    float* d = S + (BUF)*(8*WIN) + hi*WIN + col; \
    *reinterpret_cast<float4*>(d + 0*WIN) = R0; \
    *reinterpret_cast<float4*>(d + 2*WIN) = R1; \
    *reinterpret_cast<float4*>(d + 4*WIN) = R2; \
    *reinterpret_cast<float4*>(d + 6*WIN) = R3; }
#define FMA4(A, WS, XV) \
    A.x = fmaf(WS, XV.x, A.x); A.y = fmaf(WS, XV.y, A.y); \
    A.z = fmaf(WS, XV.z, A.z); A.w = fmaf(WS, XV.w, A.w);

    float4 rA0,rA1,rA2,rA3, rB0,rB1,rB2,rB3;
    // prologue: T0->A, T1->B (8 loads in flight), write T0, refill A with T2
    LOADSET(rA0,rA1,rA2,rA3, 0)
    LOADSET(rB0,rB1,rB2,rB3, 1)
    WRITESET(rA0,rA1,rA2,rA3, 0)            // waits only A's loads
    LOADSET(rA0,rA1,rA2,rA3, 2)
    __syncthreads();

#pragma unroll 2
    for (int kt=0; kt<NT; ++kt){
        // write T(kt+1) into Buf[(kt+1)&1]; issue T(kt+3) into freed set
        if (kt & 1){
            if (kt < NT-1) WRITESET(rA0,rA1,rA2,rA3, (kt+1)&1)
            if (kt < NT-3) LOADSET (rA0,rA1,rA2,rA3, kt+3)
        } else {
            if (kt < NT-1) WRITESET(rB0,rB1,rB2,rB3, (kt+1)&1)
            if (kt < NT-3) LOADSET (rB0,rB1,rB2,rB3, kt+3)
        }
        const float* X = S + (kt&1)*(8*WIN) + (l<<2);
        const int K0 = kt*8;
#pragma unroll 4
        for (int k=0; k<8; ++k){
            float w0 = w0r[K0+k], w1 = w1r[K0+k];     // s_load (uniform)
            float w2 = w2r[K0+k], w3 = w3r[K0+k];
            float4 x0 = *reinterpret_cast<const float4*>(X + k*WIN);
            float4 x1 = *reinterpret_cast<const float4*>(X + k*WIN + 256);
            FMA4(c0p0,w0,x0) FMA4(c0p1,w0,x1)
            FMA4(c1p0,w1,x0) FMA4(c1p1,w1,x1)
            FMA4(c2p0,w2,x0) FMA4(c2p1,w2,x1)
            FMA4(c3p0,w3,x0) FMA4(c3p1,w3,x1)
        }
        __syncthreads();
    }
#undef FMA4
#undef LOADSET
#undef WRITESET
#undef XADDR

    // ---- phase B: E/N for this wave's 4 channels over the 512-s window ----
#define PHB(J, A0, A1) { \
    const float* p4 = inp + ((size_t)(4*NB + b)*NC + (cf+(J)))*HW + sbase + (l<<2); \
    float4 x40 = *reinterpret_cast<const float4*>(p4); \
    float4 x41 = *reinterpret_cast<const float4*>(p4 + 256); \
    _Pragma("unroll") \
    for (int i=0; i<4; ++i){ \
        const float* pi = inp + ((size_t)((i)*NB + b)*NC + (cf+(J)))*HW + sbase + (l<<2); \
        float4 xi0 = *reinterpret_cast<const float4*>(pi); \
        float4 xi1 = *reinterpret_cast<const float4*>(pi + 256); \
        float dx,dy,dz,dw,e,n; \
        dx=x40.x-xi0.x; dy=x40.y-xi0.y; dz=x40.z-xi0.z; dw=x40.w-xi0.w; \
        n = fmaf(dx,dx, fmaf(dy,dy, fmaf(dz,dz, dw*dw))); \
        e = fmaf((A0).x,dx, fmaf((A0).y,dy, fmaf((A0).z,dz, (A0).w*dw))); \
        dx=x41.x-xi1.x; dy=x41.y-xi1.y; dz=x41.z-xi1.z; dw=x41.w-xi1.w; \
        n = fmaf(dx,dx, fmaf(dy,dy, fmaf(dz,dz, fmaf(dw,dw, n)))); \
        e = fmaf((A1).x,dx, fmaf((A1).y,dy, fmaf((A1).z,dz, fmaf((A1).w,dw, e)))); \
        e = redsum64(e); n = redsum64(n); \
        if (l == 0){ \
            float* p = EN + ((size_t)b*NC + cf + (J))*8; \
            atomicAdd(p + i, e); atomicAdd(p + 4 + i, n); \
        } \
    } }

    PHB(0, c0p0, c0p1) PHB(1, c1p0, c1p1)
    PHB(2, c2p0, c2p1) PHB(3, c3p0, c3p1)
#undef PHB
}

// ---------------- k3: finalize coefs (inlined k2) + y += alpha . inp ----------------
// 2048 blocks = (b:8) x (ck:16 chunks of 1024 floats) x (rg:16 groups of 20
// rows); 256 thr, __launch_bounds__(256,8) -> 8 blocks/CU, 32 waves/CU (2x
// round 4). Per row the block reads one contiguous 4 KB burst. Prologue
// recomputes the 320 alpha coefs from EN. Finish: 4 atomicAdds/thread into
// zero-initialized y; bias added by rg==0 only.
__global__ __launch_bounds__(256, 8) void k3_out(const float* __restrict__ inp,
        const float* __restrict__ EN, const float* __restrict__ out_w,
        const float* __restrict__ out_b, float* __restrict__ y)
{
    __shared__ float Al[NK];
    const int tid = threadIdx.x;
    const int blk = blockIdx.x;
    const int b   = blk >> 8;            // 0..7
    const int ck  = (blk >> 4) & 15;     // 0..15: 1024-float chunk
    const int rg  = blk & 15;            // 0..15: 20-row group
    const int s0  = ck << 10;

    if (tid < 64){          // inline k2: coefs for channel c = tid
        const int c = tid;
        const float* e = EN + ((size_t)b*NC + c)*8;
        float w1 = out_w[c], w2 = out_w[NC + c];
        float csum = 0.f;
#pragma unroll
        for (int i=0; i<4; ++i){
            float nc = fmaxf(sqrtf(e[4+i]), 1e-12f);
            float coef = e[i] / (nc*nc);
            Al[i*NC + c] = -w1*coef;
            csum += coef;
        }
        Al[4*NC + c] = w1*csum + w2;
    }
    __syncthreads();

    float4 acc;
    if (rg == 0){ float bb = out_b[0]; acc = make_float4(bb,bb,bb,bb); }
    else        { acc = make_float4(0.f,0.f,0.f,0.f); }

    const int rbase = rg*20;
#pragma unroll 4
    for (int j=0; j<20; ++j){
        int r = rbase + j;                                   // uniform per block
        const float* p = inp + ((size_t)((r>>6)*NB + b)*NC + (r&63))*HW + s0 + (tid<<2);
        float  w  = Al[r];                                   // uniform broadcast
        float4 xv = *reinterpret_cast<const float4*>(p);
        acc.x = fmaf(w, xv.x, acc.x); acc.y = fmaf(w, xv.y, acc.y);
        acc.z = fmaf(w, xv.z, acc.z); acc.w = fmaf(w, xv.w, acc.w);
    }
    float* yp = y + (size_t)b*HW + s0 + (tid<<2);
    atomicAdd(yp+0, acc.x);
    atomicAdd(yp+1, acc.y);
    atomicAdd(yp+2, acc.z);
    atomicAdd(yp+3, acc.w);
}

extern "C" void kernel_launch(void* const* d_in, const int* in_sizes, int n_in,
                              void* d_out, int out_size, void* d_ws, size_t ws_size,
                              hipStream_t stream)
{
    const float* inp      = (const float*)d_in[0];
    const float* origin_w = (const float*)d_in[1];
    const float* origin_b = (const float*)d_in[2];
    const float* out_w    = (const float*)d_in[3];
    const float* out_b    = (const float*)d_in[4];
    float* y  = (float*)d_out;
    float* EN = (float*)d_ws;            // 4096 floats

    k0z     <<<65,   256, 0, stream>>>(EN, y);
    k1_fused<<<1024, 256, 0, stream>>>(inp, origin_w, origin_b, EN);
    k3_out  <<<2048, 256, 0, stream>>>(inp, EN, out_w, out_b, y);
}